// Round 1
// 539.216 us; speedup vs baseline: 1.0063x; 1.0063x over previous
//
#include <hip/hip_runtime.h>

// BSpline basis expansion: N = 2097152 points, 64 cubic B-spline columns,
// uniform knots linspace(-1,1,68), degree 3. Output (N,64) FP32 row-major.
// R14: 602.6 -> R16 (+nt): 572.8 -> R17 (8 cols/thread): 550.0 ->
// R18 (wave-tile contiguous stores): 542.6.
//
// Math: uniform unclamped knots => col j is the cardinal cubic B-spline.
// Only cols i-3..i nonzero, i = floor((x+1)*33.5), t = s - i:
//   w0=(1-t)^3/6, w1=(3t^3-6t^2+4)/6, w2=(-3t^3+3t^2+3t+1)/6, w3=t^3/6.
//
// R19 tests launch-granularity: R18 ran 262,144 one-shot waves, each with
// only 2 stores between its fixed costs (WG launch, sniff+ballot, x-load
// latency, vmcnt drain at endpgm) -> effective write BW ~2.7-4.4 TB/s vs
// the 6.2 TB/s the harness's own fill kernel proves achievable. Fix:
// persistent grid-stride, 2048 blocks (8/CU, full 32-wave occupancy),
// 8192 waves x 16 tiles. Per iteration a wave owns 256 slots (4 KiB) and
// issues 4 nt stores, each 1 KiB CONTIGUOUS across the wave; sniff and
// lane decomposition hoisted. Predict kernel ~90-110 us, bench ~495-515.

typedef float v4f __attribute__((ext_vector_type(4)));

__device__ __forceinline__ float bf16bits_to_f32(unsigned short h) {
    union { unsigned int u; float f; } c;
    c.u = ((unsigned int)h) << 16;
    return c.f;
}

__device__ __forceinline__ float wsel(int d, float w0, float w1, float w2,
                                      float w3) {
    return (d == 0) ? w0 : (d == 1) ? w1 : (d == 2) ? w2 : (d == 3) ? w3
                                                                    : 0.0f;
}

__device__ __forceinline__ v4f bspline_seg(float x, int c0 /*4-aligned col*/) {
    // 4-col segment [c0, c0+3] of the 64-col cardinal cubic basis row.
    x = fminf(fmaxf(x, -1.0f), 0.99999988f);  // clip(DMIN, DMAX-1e-7)
    float s = (x + 1.0f) * 33.5f;             // 1/h = 67/2
    int i = (int)floorf(s);
    i = i < 0 ? 0 : (i > 66 ? 66 : i);
    float t = s - (float)i;

    float t2 = t * t;
    float t3 = t2 * t;
    float omt = 1.0f - t;
    float w0 = (omt * omt * omt) * (1.0f / 6.0f);
    float w1 = (3.0f * t3 - 6.0f * t2 + 4.0f) * (1.0f / 6.0f);
    float w2 = (-3.0f * t3 + 3.0f * t2 + 3.0f * t + 1.0f) * (1.0f / 6.0f);
    float w3 = t3 * (1.0f / 6.0f);

    int base = i - 3;  // column receiving w0
    v4f o;
    o.x = wsel(c0 + 0 - base, w0, w1, w2, w3);
    o.y = wsel(c0 + 1 - base, w0, w1, w2, w3);
    o.z = wsel(c0 + 2 - base, w0, w1, w2, w3);
    o.w = wsel(c0 + 3 - base, w0, w1, w2, w3);
    return o;
}

__global__ __launch_bounds__(256) void BSpline_16466904613521_kernel(
        const void* __restrict__ x_in, v4f* __restrict__ out, int n_slots) {
    // --- wave-level input-dtype sniff, once per wave (no barriers) ---
    const unsigned int lane = threadIdx.x & 63u;
    float sv = bf16bits_to_f32(((const unsigned short*)x_in)[lane]);
    bool implausible = !(sv == sv) || fabsf(sv) > 1.0f;
    const bool is_f32 = (__ballot(implausible) != 0ull);  // wave-uniform

    // Lane decomposition, loop-invariant:
    //   slot s = tile*256 + 64k + lane  (k = 0..3)
    //   q = s & 15 = lane & 15  (4-col segment, constant per lane)
    //   row = s >> 4 = tile*16 + 4k + (lane >> 4)
    const int c0 = (int)(lane & 15u) << 2;
    const int lhi = (int)(lane >> 4);

    const int wave = blockIdx.x * (int)(blockDim.x >> 6) +
                     (int)(threadIdx.x >> 6);
    const int n_waves = (int)gridDim.x * (int)(blockDim.x >> 6);
    const int n_tiles = (n_slots + 255) >> 8;  // 256-slot (4 KiB) wave tiles

    for (int tile = wave; tile < n_tiles; tile += n_waves) {
        const int s0 = (tile << 8) | (int)lane;
        const int r0 = (tile << 4) + lhi;
        const bool full = ((tile << 8) + 256) <= n_slots;  // wave-uniform

        if (full) {
            float xr0, xr1, xr2, xr3;
            if (is_f32) {  // wave-uniform branch
                const float* xf = (const float*)x_in;
                xr0 = xf[r0];
                xr1 = xf[r0 + 4];
                xr2 = xf[r0 + 8];
                xr3 = xf[r0 + 12];
            } else {
                const unsigned short* xb = (const unsigned short*)x_in;
                xr0 = bf16bits_to_f32(xb[r0]);
                xr1 = bf16bits_to_f32(xb[r0 + 4]);
                xr2 = bf16bits_to_f32(xb[r0 + 8]);
                xr3 = bf16bits_to_f32(xb[r0 + 12]);
            }
            v4f o0 = bspline_seg(xr0, c0);
            v4f o1 = bspline_seg(xr1, c0);
            v4f o2 = bspline_seg(xr2, c0);
            v4f o3 = bspline_seg(xr3, c0);
            // 4 nt stores, each 1 KiB contiguous across the wave.
            __builtin_nontemporal_store(o0, &out[s0]);
            __builtin_nontemporal_store(o1, &out[s0 + 64]);
            __builtin_nontemporal_store(o2, &out[s0 + 128]);
            __builtin_nontemporal_store(o3, &out[s0 + 192]);
        } else {
            // Tail tile (not hit for N=2M: 33.5M slots = 131072 full tiles).
#pragma unroll
            for (int k = 0; k < 4; ++k) {
                int s = s0 + 64 * k;
                if (s < n_slots) {
                    int r = r0 + 4 * k;
                    float xv = is_f32
                        ? ((const float*)x_in)[r]
                        : bf16bits_to_f32(((const unsigned short*)x_in)[r]);
                    __builtin_nontemporal_store(bspline_seg(xv, c0), &out[s]);
                }
            }
        }
    }
}

extern "C"
__attribute__((visibility("default")))
void kernel_launch(void* const* d_in, const int* in_sizes, int n_in,
                   void* d_out, int out_size, void* d_ws, size_t ws_size,
                   hipStream_t stream) {
    (void)in_sizes; (void)n_in; (void)d_ws; (void)ws_size;
    const void* x = d_in[0];
    int n_slots = out_size >> 2;  // total v4f slots = N*64/4 = 33.5M
    int n_tiles = (n_slots + 255) >> 8;

    int block = 256;                         // 4 waves
    int grid = 2048;                         // 8 blocks/CU -> 32 waves/CU
    int max_grid = (n_tiles + 3) >> 2;       // never more waves than tiles
    if (grid > max_grid) grid = max_grid;

    BSpline_16466904613521_kernel<<<grid, block, 0, stream>>>(
        x, (v4f*)d_out, n_slots);
}